// Round 2
// baseline (711.066 us; speedup 1.0000x reference)
//
#include <hip/hip_runtime.h>
#include <hip/hip_bf16.h>
#include <math.h>

typedef unsigned int u32;
typedef unsigned long long u64;

#define NN 50000
#define NE 800000
#define ET (NE + NN)          // edges + self loops
#define TOPK 8

__device__ __forceinline__ u64 shflxor64(u64 v, int m) {
    int lo = __shfl_xor((int)(u32)v, m);
    int hi = __shfl_xor((int)(u32)(v >> 32), m);
    return ((u64)(u32)hi << 32) | (u32)lo;
}

// ---------------- h = x @ W  (f32 in, f32 out) ----------------
// block: 256 thr, 64 rows/block; W (128x128 f32, 64 KB) staged in LDS.
__global__ __launch_bounds__(256) void gemm_k(const float* __restrict__ x,
                                              const float* __restrict__ W,
                                              float* __restrict__ hbuf) {
    __shared__ float lw[128 * 128];   // 64 KB
    __shared__ float lx[64 * 129];    // 33 KB (pad +1 breaks bank conflicts)
    const int t = threadIdx.x;
    const int rbase = blockIdx.x * 64;

    for (int i = t * 4; i < 16384; i += 1024) {
        float4 v = *reinterpret_cast<const float4*>(W + i);
        lw[i] = v.x; lw[i + 1] = v.y; lw[i + 2] = v.z; lw[i + 3] = v.w;
    }
    for (int i = t * 4; i < 8192; i += 1024) {
        int r = i >> 7, k = i & 127;
        float4 v = make_float4(0.f, 0.f, 0.f, 0.f);
        if (rbase + r < NN)
            v = *reinterpret_cast<const float4*>(x + (size_t)(rbase + r) * 128 + k);
        float* dst = lx + r * 129 + k;
        dst[0] = v.x; dst[1] = v.y; dst[2] = v.z; dst[3] = v.w;
    }
    __syncthreads();

    const int cx = t & 15;        // output cols cx*8 .. +7
    const int ry = t >> 4;        // rows ry*4 .. +3
    float acc[4][8];
    #pragma unroll
    for (int i = 0; i < 4; ++i)
        #pragma unroll
        for (int j = 0; j < 8; ++j) acc[i][j] = 0.f;

    for (int k = 0; k < 128; ++k) {
        float4 wa = *reinterpret_cast<const float4*>(lw + k * 128 + cx * 8);
        float4 wb = *reinterpret_cast<const float4*>(lw + k * 128 + cx * 8 + 4);
        float wv[8] = {wa.x, wa.y, wa.z, wa.w, wb.x, wb.y, wb.z, wb.w};
        #pragma unroll
        for (int i = 0; i < 4; ++i) {
            float xv = lx[(ry * 4 + i) * 129 + k];
            #pragma unroll
            for (int j = 0; j < 8; ++j) acc[i][j] += xv * wv[j];
        }
    }
    #pragma unroll
    for (int i = 0; i < 4; ++i) {
        int rr = rbase + ry * 4 + i;
        if (rr < NN) {
            float* dst = hbuf + (size_t)rr * 128 + cx * 8;
            *reinterpret_cast<float4*>(dst)     = make_float4(acc[i][0], acc[i][1], acc[i][2], acc[i][3]);
            *reinterpret_cast<float4*>(dst + 4) = make_float4(acc[i][4], acc[i][5], acc[i][6], acc[i][7]);
        }
    }
}

// ---------------- per-node attention scalars ----------------
// s_i[n,h] = dot(h[n,h,:], att[h,:32]); s_j[n,h] = dot(h[n,h,:], att[h,32:])
__global__ __launch_bounds__(256) void s_k(const float* __restrict__ hbuf,
                                           const float* __restrict__ att,
                                           float* __restrict__ s_i,
                                           float* __restrict__ s_j) {
    __shared__ float ai[4][33], aj[4][33];
    const int t = threadIdx.x;
    {
        int hh = t >> 6, c = t & 63;   // att is 4x64 = 256 floats
        float v = att[t];
        if (c < 32) ai[hh][c] = v; else aj[hh][c - 32] = v;
    }
    __syncthreads();
    int idx = blockIdx.x * 256 + t;
    if (idx >= NN * 4) return;
    int n = idx >> 2, hh = idx & 3;
    const float* hp = hbuf + (size_t)n * 128 + hh * 32;
    float si = 0.f, sj = 0.f;
    #pragma unroll
    for (int c = 0; c < 32; c += 4) {
        float4 hv = *reinterpret_cast<const float4*>(hp + c);
        si += hv.x * ai[hh][c] + hv.y * ai[hh][c + 1] + hv.z * ai[hh][c + 2] + hv.w * ai[hh][c + 3];
        sj += hv.x * aj[hh][c] + hv.y * aj[hh][c + 1] + hv.z * aj[hh][c + 2] + hv.w * aj[hh][c + 3];
    }
    s_i[idx] = si;
    s_j[idx] = sj;
}

// ---------------- degree count (real edges only) ----------------
__global__ __launch_bounds__(256) void deg_k(const int* __restrict__ ei,
                                             int* __restrict__ deg) {
    int e = blockIdx.x * 256 + threadIdx.x;
    if (e >= NE) return;
    atomicAdd(deg + ei[e], 1);
}

// ---------------- single-block exclusive scan of (deg[i]+1) ----------------
__global__ __launch_bounds__(1024) void scan_k(const int* __restrict__ deg,
                                               int* __restrict__ offs,
                                               int* __restrict__ cursor) {
    const int CH = 49;  // ceil(50000/1024)
    const int t = threadIdx.x;
    const int lane = t & 63, wid = t >> 6;
    int lo = t * CH, hi = min(lo + CH, NN);
    int s = 0;
    for (int i = lo; i < hi; ++i) s += deg[i] + 1;   // +1 self loop
    int v = s;
    #pragma unroll
    for (int off = 1; off < 64; off <<= 1) {
        int o = __shfl_up(v, off);
        if (lane >= off) v += o;
    }
    __shared__ int wsum[16], wpre[16];
    if (lane == 63) wsum[wid] = v;
    __syncthreads();
    if (t == 0) {
        int acc = 0;
        #pragma unroll
        for (int i = 0; i < 16; ++i) { wpre[i] = acc; acc += wsum[i]; }
        offs[NN] = acc;   // == ET
    }
    __syncthreads();
    int run = v - s + wpre[wid];
    for (int i = lo; i < hi; ++i) {
        offs[i] = run;
        cursor[i] = run;
        run += deg[i] + 1;
    }
}

// ---------------- CSR scatter (edges + self loops) ----------------
__global__ __launch_bounds__(256) void scatter_k(const int* __restrict__ ei,
                                                 int* __restrict__ cursor,
                                                 int* __restrict__ csr) {
    int e = blockIdx.x * 256 + threadIdx.x;
    if (e >= ET) return;
    int r = (e < NE) ? ei[e] : e - NE;
    int pos = atomicAdd(cursor + r, 1);
    csr[pos] = e;
}

// ---------------- fused row: top-k + softmax + aggregate + ELU ----------------
// one 256-thread block per row (grid-stride); wave w == head w.
// top-k by s_j[col,h] (leaky_relu(s_i+s_j) is strictly monotone in s_j,
// s_i constant within a row segment -> identical selection & tie-break).
__global__ __launch_bounds__(256) void row_k(const int* __restrict__ ei,
                                             const int* __restrict__ offs,
                                             const int* __restrict__ csr,
                                             const float* __restrict__ s_i,
                                             const float* __restrict__ s_j,
                                             const float* __restrict__ hbuf,
                                             float* __restrict__ out) {
    __shared__ int lcol[256];
    __shared__ int leid[256];
    __shared__ float lsj[4][256];
    const int t = threadIdx.x;
    const int lane = t & 63;
    const int hh = t >> 6;  // wave id == head

    for (int r = blockIdx.x; r < NN; r += gridDim.x) {
        int o0 = offs[r];
        int deg = offs[r + 1] - o0;
        if (deg > 256) deg = 256;  // P(deg>256) ~ 0 for Binomial(800k, 1/50k)
        __syncthreads();           // protect LDS reuse across row iterations
        for (int j = t; j < deg; j += 256) {
            int eid = csr[o0 + j];
            leid[j] = eid;
            int col = (eid < NE) ? ei[NE + eid] : r;
            lcol[j] = col;
            float4 sj = *reinterpret_cast<const float4*>(s_j + (size_t)col * 4);
            lsj[0][j] = sj.x; lsj[1][j] = sj.y; lsj[2][j] = sj.z; lsj[3][j] = sj.w;
        }
        __syncthreads();

        // per-lane keys: (sortable-float << 32) | ~eid  -> larger s_j wins,
        // ties -> smaller original edge index (matches lexsort stability)
        u64 key[4];
        #pragma unroll
        for (int s = 0; s < 4; ++s) {
            int j = lane + 64 * s;
            if (j < deg) {
                u32 b = __float_as_uint(lsj[hh][j]);
                u32 fk = (b & 0x80000000u) ? ~b : (b | 0x80000000u);
                key[s] = ((u64)fk << 32) | (u32)(~(u32)leid[j]);
            } else {
                key[s] = 0ull;
            }
        }

        float kv[TOPK];   // s_j value of kept edge
        int kc[TOPK];     // col of kept edge
        int nkeep = 0;
        for (int it = 0; it < TOPK; ++it) {
            u64 lk = 0ull; int ls = 0;
            #pragma unroll
            for (int s = 0; s < 4; ++s)
                if (key[s] > lk) { lk = key[s]; ls = s; }
            u64 wk = lk;
            #pragma unroll
            for (int off = 32; off >= 1; off >>= 1) {
                u64 o = shflxor64(wk, off);
                if (o > wk) wk = o;
            }
            if (wk == 0ull) break;     // wave-uniform (wk uniform after butterfly)
            bool own = (lk == wk);     // unique: eid embedded in key
            u64 bal = __ballot(own);
            int owner = __ffsll((long long)bal) - 1;
            int myj = ls * 64 + lane;
            int j = __shfl(myj, owner);
            u32 fk = (u32)(wk >> 32);
            u32 b = (fk & 0x80000000u) ? (fk ^ 0x80000000u) : ~fk;
            kv[nkeep] = __uint_as_float(b);
            kc[nkeep] = lcol[j];
            ++nkeep;
            if (own) key[ls] = 0ull;
        }

        // actual logits for kept: e = leaky_relu(s_i[r,h] + s_j); kv[0] is max
        float si = s_i[(size_t)r * 4 + hh];
        float ev[TOPK];
        for (int k2 = 0; k2 < nkeep; ++k2) {
            float e = si + kv[k2];
            ev[k2] = (e >= 0.f) ? e : 0.2f * e;
        }
        float m = ev[0];
        float al[TOPK];
        float denom = 0.f;
        for (int k2 = 0; k2 < nkeep; ++k2) { al[k2] = __expf(ev[k2] - m); denom += al[k2]; }
        float inv = 1.f / denom;

        // weighted aggregate: lanes 0..31 even terms, 32..63 odd terms
        int c = lane & 31, half = lane >> 5;
        float acc = 0.f;
        for (int k2 = half; k2 < nkeep; k2 += 2)
            acc += al[k2] * hbuf[(size_t)kc[k2] * 128 + hh * 32 + c];
        acc += __shfl_xor(acc, 32);
        if (half == 0) {
            float o = acc * inv;
            o = (o > 0.f) ? o : expm1f(o);   // ELU
            out[(size_t)r * 128 + hh * 32 + c] = o;
        }
    }
}

extern "C" void kernel_launch(void* const* d_in, const int* in_sizes, int n_in,
                              void* d_out, int out_size, void* d_ws, size_t ws_size,
                              hipStream_t stream) {
    const float* x   = (const float*)d_in[0];   // 50000x128 f32
    const float* W   = (const float*)d_in[1];   // 128x128  f32
    const float* att = (const float*)d_in[2];   // 4x64     f32
    const int*   ei  = (const int*)d_in[3];     // 2x800000 int32
    float* out = (float*)d_out;                 // 50000x128 f32

    float* hbuf  = (float*)d_ws;                // 6.4M f32  (25.6 MB)
    float* s_i   = hbuf + 6400000;              // 200k f32
    float* s_j   = s_i + 200000;                // 200k f32
    int* deg     = (int*)(s_j + 200000);        // 50k
    int* offs    = deg + NN;                    // 50001
    int* cursor  = offs + NN + 1;               // 50k
    int* csr     = cursor + NN;                 // 850k
    // total ws: ~31.2 MB

    hipMemsetAsync(deg, 0, NN * sizeof(int), stream);
    gemm_k<<<(NN + 63) / 64, 256, 0, stream>>>(x, W, hbuf);
    s_k<<<(NN * 4 + 255) / 256, 256, 0, stream>>>(hbuf, att, s_i, s_j);
    deg_k<<<(NE + 255) / 256, 256, 0, stream>>>(ei, deg);
    scan_k<<<1, 1024, 0, stream>>>(deg, offs, cursor);
    scatter_k<<<(ET + 255) / 256, 256, 0, stream>>>(ei, cursor, csr);
    row_k<<<10240, 256, 0, stream>>>(ei, offs, csr, s_i, s_j, hbuf, out);
}

// Round 3
// 392.522 us; speedup vs baseline: 1.8115x; 1.8115x over previous
//
#include <hip/hip_runtime.h>
#include <math.h>

typedef unsigned int u32;
typedef unsigned long long u64;

#define NN 50000
#define NE 800000
#define ET (NE + NN)          // edges + self loops
#define TOPK 8

// ---------------- h = x @ W  (f32 in, f32 out) ----------------
// block: 256 thr, 64 rows/block; W (128x128 f32, 64 KB) staged in LDS.
__global__ __launch_bounds__(256) void gemm_k(const float* __restrict__ x,
                                              const float* __restrict__ W,
                                              float* __restrict__ hbuf) {
    __shared__ float lw[128 * 128];   // 64 KB
    __shared__ float lx[64 * 129];    // 33 KB (pad +1 breaks bank conflicts)
    const int t = threadIdx.x;
    const int rbase = blockIdx.x * 64;

    for (int i = t * 4; i < 16384; i += 1024) {
        float4 v = *reinterpret_cast<const float4*>(W + i);
        lw[i] = v.x; lw[i + 1] = v.y; lw[i + 2] = v.z; lw[i + 3] = v.w;
    }
    for (int i = t * 4; i < 8192; i += 1024) {
        int r = i >> 7, k = i & 127;
        float4 v = make_float4(0.f, 0.f, 0.f, 0.f);
        if (rbase + r < NN)
            v = *reinterpret_cast<const float4*>(x + (size_t)(rbase + r) * 128 + k);
        float* dst = lx + r * 129 + k;
        dst[0] = v.x; dst[1] = v.y; dst[2] = v.z; dst[3] = v.w;
    }
    __syncthreads();

    const int cx = t & 15;        // output cols cx*8 .. +7
    const int ry = t >> 4;        // rows ry*4 .. +3
    float acc[4][8];
    #pragma unroll
    for (int i = 0; i < 4; ++i)
        #pragma unroll
        for (int j = 0; j < 8; ++j) acc[i][j] = 0.f;

    for (int k = 0; k < 128; ++k) {
        float4 wa = *reinterpret_cast<const float4*>(lw + k * 128 + cx * 8);
        float4 wb = *reinterpret_cast<const float4*>(lw + k * 128 + cx * 8 + 4);
        float wv[8] = {wa.x, wa.y, wa.z, wa.w, wb.x, wb.y, wb.z, wb.w};
        #pragma unroll
        for (int i = 0; i < 4; ++i) {
            float xv = lx[(ry * 4 + i) * 129 + k];
            #pragma unroll
            for (int j = 0; j < 8; ++j) acc[i][j] += xv * wv[j];
        }
    }
    #pragma unroll
    for (int i = 0; i < 4; ++i) {
        int rr = rbase + ry * 4 + i;
        if (rr < NN) {
            float* dst = hbuf + (size_t)rr * 128 + cx * 8;
            *reinterpret_cast<float4*>(dst)     = make_float4(acc[i][0], acc[i][1], acc[i][2], acc[i][3]);
            *reinterpret_cast<float4*>(dst + 4) = make_float4(acc[i][4], acc[i][5], acc[i][6], acc[i][7]);
        }
    }
}

// ---------------- per-node attention scalars ----------------
__global__ __launch_bounds__(256) void s_k(const float* __restrict__ hbuf,
                                           const float* __restrict__ att,
                                           float* __restrict__ s_i,
                                           float* __restrict__ s_j) {
    __shared__ float ai[4][33], aj[4][33];
    const int t = threadIdx.x;
    {
        int hh = t >> 6, c = t & 63;   // att is 4x64 = 256 floats
        float v = att[t];
        if (c < 32) ai[hh][c] = v; else aj[hh][c - 32] = v;
    }
    __syncthreads();
    int idx = blockIdx.x * 256 + t;
    if (idx >= NN * 4) return;
    int n = idx >> 2, hh = idx & 3;
    const float* hp = hbuf + (size_t)n * 128 + hh * 32;
    float si = 0.f, sj = 0.f;
    #pragma unroll
    for (int c = 0; c < 32; c += 4) {
        float4 hv = *reinterpret_cast<const float4*>(hp + c);
        si += hv.x * ai[hh][c] + hv.y * ai[hh][c + 1] + hv.z * ai[hh][c + 2] + hv.w * ai[hh][c + 3];
        sj += hv.x * aj[hh][c] + hv.y * aj[hh][c + 1] + hv.z * aj[hh][c + 2] + hv.w * aj[hh][c + 3];
    }
    s_i[idx] = si;
    s_j[idx] = sj;
}

// ---------------- degree count (real edges only) ----------------
__global__ __launch_bounds__(256) void deg_k(const int* __restrict__ ei,
                                             int* __restrict__ deg) {
    int e = blockIdx.x * 256 + threadIdx.x;
    if (e >= NE) return;
    atomicAdd(deg + ei[e], 1);
}

// ---------------- single-block exclusive scan of (deg[i]+1) ----------------
__global__ __launch_bounds__(1024) void scan_k(const int* __restrict__ deg,
                                               int* __restrict__ offs,
                                               int* __restrict__ cursor) {
    const int CH = 49;  // ceil(50000/1024)
    const int t = threadIdx.x;
    const int lane = t & 63, wid = t >> 6;
    int lo = t * CH, hi = min(lo + CH, NN);
    int s = 0;
    for (int i = lo; i < hi; ++i) s += deg[i] + 1;   // +1 self loop
    int v = s;
    #pragma unroll
    for (int off = 1; off < 64; off <<= 1) {
        int o = __shfl_up(v, off);
        if (lane >= off) v += o;
    }
    __shared__ int wsum[16], wpre[16];
    if (lane == 63) wsum[wid] = v;
    __syncthreads();
    if (t == 0) {
        int acc = 0;
        #pragma unroll
        for (int i = 0; i < 16; ++i) { wpre[i] = acc; acc += wsum[i]; }
        offs[NN] = acc;   // == ET
    }
    __syncthreads();
    int run = v - s + wpre[wid];
    for (int i = lo; i < hi; ++i) {
        offs[i] = run;
        cursor[i] = run;
        run += deg[i] + 1;
    }
}

// ---------------- CSR scatter (edges + self loops), also emits col ----------------
__global__ __launch_bounds__(256) void scatter_k(const int* __restrict__ ei,
                                                 int* __restrict__ cursor,
                                                 int* __restrict__ csr,
                                                 int* __restrict__ ccol) {
    int e = blockIdx.x * 256 + threadIdx.x;
    if (e >= ET) return;
    int r, c;
    if (e < NE) { r = ei[e]; c = ei[NE + e]; } else { r = e - NE; c = r; }
    int pos = atomicAdd(cursor + r, 1);
    csr[pos] = e;
    ccol[pos] = c;
}

// ---------------- fused: per-lane top-k+softmax, per-wave aggregate ----------------
// phase 1: thread t handles (row = rbase + t/4, head = t&3) serially:
//   insertion top-8 by u64 key (sortable-float(s_j) << 32 | ~eid) — exact
//   lexsort order (larger e wins, ties -> smaller eid; leaky_relu(s_i+s_j)
//   strictly monotone in s_j, s_i row-constant => select by s_j).
// phase 2: wave w aggregates rows rbase + w*16 .. +15 with coalesced 128 B
//   gathers of h[col], ELU, store.
__global__ __launch_bounds__(256) void rowsel_k(const int* __restrict__ offs,
                                                const int* __restrict__ csr,
                                                const int* __restrict__ ccol,
                                                const float* __restrict__ s_i,
                                                const float* __restrict__ s_j,
                                                const float* __restrict__ hbuf,
                                                float* __restrict__ out) {
    __shared__ float lal[256 * 8];   // alpha (already /denom)
    __shared__ int   lcl[256 * 8];   // col
    const int t = threadIdx.x;
    const int rbase = blockIdx.x * 64;
    const int row = rbase + (t >> 2);
    const int head = t & 3;

    if (row < NN) {
        int o0 = offs[row];
        int dg = offs[row + 1] - o0;
        u64 kl[TOPK]; int cl[TOPK];
        #pragma unroll
        for (int i = 0; i < TOPK; ++i) { kl[i] = 0ull; cl[i] = 0; }
        for (int j = 0; j < dg; ++j) {
            int eid = csr[o0 + j];
            int col = ccol[o0 + j];
            float v = s_j[(size_t)col * 4 + head];
            u32 b = __float_as_uint(v);
            u32 fk = (b & 0x80000000u) ? ~b : (b | 0x80000000u);
            u64 key = ((u64)fk << 32) | (u32)(~(u32)eid);
            #pragma unroll
            for (int i = 0; i < TOPK; ++i) {
                bool gt = key > kl[i];
                u64 tk = gt ? kl[i] : key;  kl[i] = gt ? key : kl[i];  key = tk;
                int tc = gt ? cl[i] : col;  cl[i] = gt ? col : cl[i];  col = tc;
            }
        }
        int nk = (dg < TOPK) ? dg : TOPK;
        float si = s_i[(size_t)row * 4 + head];
        float al[TOPK];
        float m = 0.f;
        #pragma unroll
        for (int i = 0; i < TOPK; ++i) {
            u32 fk = (u32)(kl[i] >> 32);
            u32 b = (fk & 0x80000000u) ? (fk ^ 0x80000000u) : ~fk;
            float v = __uint_as_float(b);
            float e = si + v;
            e = (e >= 0.f) ? e : 0.2f * e;
            al[i] = e;
            if (i == 0) m = e;      // kl[0] is the max key -> max e
        }
        float denom = 0.f;
        #pragma unroll
        for (int i = 0; i < TOPK; ++i) {
            float z = (i < nk) ? __expf(al[i] - m) : 0.f;
            al[i] = z; denom += z;
        }
        float inv = 1.f / denom;
        #pragma unroll
        for (int i = 0; i < TOPK; ++i) {
            lal[t * 8 + i] = al[i] * inv;
            lcl[t * 8 + i] = cl[i];
        }
    }
    __syncthreads();

    const int lane = t & 63;
    const int wid = t >> 6;
    const int c = lane & 31, half = lane >> 5;
    for (int i = 0; i < 16; ++i) {
        int lr = wid * 16 + i;
        int r = rbase + lr;
        if (r >= NN) break;          // r uniform per wave
        #pragma unroll
        for (int hh = 0; hh < 4; ++hh) {
            int lrh = (lr * 4 + hh) * 8;
            float acc = 0.f;
            #pragma unroll
            for (int k2 = half; k2 < TOPK; k2 += 2) {
                float a = lal[lrh + k2];
                int col = lcl[lrh + k2];
                acc += a * hbuf[(size_t)col * 128 + hh * 32 + c];
            }
            acc += __shfl_xor(acc, 32);
            if (half == 0) {
                float o = acc;
                o = (o > 0.f) ? o : expm1f(o);   // ELU
                out[(size_t)r * 128 + hh * 32 + c] = o;
            }
        }
    }
}

extern "C" void kernel_launch(void* const* d_in, const int* in_sizes, int n_in,
                              void* d_out, int out_size, void* d_ws, size_t ws_size,
                              hipStream_t stream) {
    const float* x   = (const float*)d_in[0];   // 50000x128 f32
    const float* W   = (const float*)d_in[1];   // 128x128  f32
    const float* att = (const float*)d_in[2];   // 4x64     f32
    const int*   ei  = (const int*)d_in[3];     // 2x800000 int32
    float* out = (float*)d_out;                 // 50000x128 f32

    float* hbuf  = (float*)d_ws;                // 6.4M f32  (25.6 MB)
    float* s_i   = hbuf + 6400000;              // 200k f32
    float* s_j   = s_i + 200000;                // 200k f32
    int* deg     = (int*)(s_j + 200000);        // 50k
    int* offs    = deg + NN;                    // 50001
    int* cursor  = offs + NN + 1;               // 50k
    int* csr     = cursor + NN;                 // 850k
    int* ccol    = csr + ET;                    // 850k
    // total ws: ~34.8 MB

    hipMemsetAsync(deg, 0, NN * sizeof(int), stream);
    gemm_k<<<(NN + 63) / 64, 256, 0, stream>>>(x, W, hbuf);
    s_k<<<(NN * 4 + 255) / 256, 256, 0, stream>>>(hbuf, att, s_i, s_j);
    deg_k<<<(NE + 255) / 256, 256, 0, stream>>>(ei, deg);
    scan_k<<<1, 1024, 0, stream>>>(deg, offs, cursor);
    scatter_k<<<(ET + 255) / 256, 256, 0, stream>>>(ei, cursor, csr, ccol);
    rowsel_k<<<(NN + 63) / 64, 256, 0, stream>>>(offs, csr, ccol, s_i, s_j, hbuf, out);
}

// Round 4
// 292.333 us; speedup vs baseline: 2.4324x; 1.3427x over previous
//
#include <hip/hip_runtime.h>
#include <math.h>

typedef unsigned int u32;
typedef unsigned long long u64;

#define NN 50000
#define NE 800000
#define ET (NE + NN)          // edges + self loops
#define TOPK 8
#define SCAN_B 196            // ceil(50000/256)

// ---------------- h = x @ W  (f32 in, f32 out) ----------------
// block: 256 thr, 64 rows/block; W (128x128 f32, 64 KB) staged in LDS.
__global__ __launch_bounds__(256) void gemm_k(const float* __restrict__ x,
                                              const float* __restrict__ W,
                                              float* __restrict__ hbuf) {
    __shared__ float lw[128 * 128];   // 64 KB
    __shared__ float lx[64 * 129];    // 33 KB (pad +1 breaks bank conflicts)
    const int t = threadIdx.x;
    const int rbase = blockIdx.x * 64;

    for (int i = t * 4; i < 16384; i += 1024) {
        float4 v = *reinterpret_cast<const float4*>(W + i);
        lw[i] = v.x; lw[i + 1] = v.y; lw[i + 2] = v.z; lw[i + 3] = v.w;
    }
    for (int i = t * 4; i < 8192; i += 1024) {
        int r = i >> 7, k = i & 127;
        float4 v = make_float4(0.f, 0.f, 0.f, 0.f);
        if (rbase + r < NN)
            v = *reinterpret_cast<const float4*>(x + (size_t)(rbase + r) * 128 + k);
        float* dst = lx + r * 129 + k;
        dst[0] = v.x; dst[1] = v.y; dst[2] = v.z; dst[3] = v.w;
    }
    __syncthreads();

    const int cx = t & 15;        // output cols cx*8 .. +7
    const int ry = t >> 4;        // rows ry*4 .. +3
    float acc[4][8];
    #pragma unroll
    for (int i = 0; i < 4; ++i)
        #pragma unroll
        for (int j = 0; j < 8; ++j) acc[i][j] = 0.f;

    for (int k = 0; k < 128; ++k) {
        float4 wa = *reinterpret_cast<const float4*>(lw + k * 128 + cx * 8);
        float4 wb = *reinterpret_cast<const float4*>(lw + k * 128 + cx * 8 + 4);
        float wv[8] = {wa.x, wa.y, wa.z, wa.w, wb.x, wb.y, wb.z, wb.w};
        #pragma unroll
        for (int i = 0; i < 4; ++i) {
            float xv = lx[(ry * 4 + i) * 129 + k];
            #pragma unroll
            for (int j = 0; j < 8; ++j) acc[i][j] += xv * wv[j];
        }
    }
    #pragma unroll
    for (int i = 0; i < 4; ++i) {
        int rr = rbase + ry * 4 + i;
        if (rr < NN) {
            float* dst = hbuf + (size_t)rr * 128 + cx * 8;
            *reinterpret_cast<float4*>(dst)     = make_float4(acc[i][0], acc[i][1], acc[i][2], acc[i][3]);
            *reinterpret_cast<float4*>(dst + 4) = make_float4(acc[i][4], acc[i][5], acc[i][6], acc[i][7]);
        }
    }
}

// ---------------- per-node attention scalars ----------------
__global__ __launch_bounds__(256) void s_k(const float* __restrict__ hbuf,
                                           const float* __restrict__ att,
                                           float* __restrict__ s_i,
                                           float* __restrict__ s_j) {
    __shared__ float ai[4][33], aj[4][33];
    const int t = threadIdx.x;
    {
        int hh = t >> 6, c = t & 63;   // att is 4x64 = 256 floats
        float v = att[t];
        if (c < 32) ai[hh][c] = v; else aj[hh][c - 32] = v;
    }
    __syncthreads();
    int idx = blockIdx.x * 256 + t;
    if (idx >= NN * 4) return;
    int n = idx >> 2, hh = idx & 3;
    const float* hp = hbuf + (size_t)n * 128 + hh * 32;
    float si = 0.f, sj = 0.f;
    #pragma unroll
    for (int c = 0; c < 32; c += 4) {
        float4 hv = *reinterpret_cast<const float4*>(hp + c);
        si += hv.x * ai[hh][c] + hv.y * ai[hh][c + 1] + hv.z * ai[hh][c + 2] + hv.w * ai[hh][c + 3];
        sj += hv.x * aj[hh][c] + hv.y * aj[hh][c + 1] + hv.z * aj[hh][c + 2] + hv.w * aj[hh][c + 3];
    }
    s_i[idx] = si;
    s_j[idx] = sj;
}

// ---------------- degree count (real edges only) ----------------
__global__ __launch_bounds__(256) void deg_k(const int* __restrict__ ei,
                                             int* __restrict__ deg) {
    int e = blockIdx.x * 256 + threadIdx.x;
    if (e >= NE) return;
    atomicAdd(deg + ei[e], 1);
}

// ---------------- hierarchical exclusive scan of (deg[i]+1) ----------------
// stage 1: per-block scan, block-local exclusive offs + block total
__global__ __launch_bounds__(256) void scan1_k(const int* __restrict__ deg,
                                               int* __restrict__ offs,
                                               int* __restrict__ bsum) {
    const int t = threadIdx.x;
    const int lane = t & 63, wid = t >> 6;
    const int i = blockIdx.x * 256 + t;
    int val = (i < NN) ? (deg[i] + 1) : 0;
    int v = val;
    #pragma unroll
    for (int off = 1; off < 64; off <<= 1) {
        int o = __shfl_up(v, off);
        if (lane >= off) v += o;
    }
    __shared__ int wsum[4], wpre[4];
    if (lane == 63) wsum[wid] = v;
    __syncthreads();
    if (t == 0) {
        int acc = 0;
        #pragma unroll
        for (int w = 0; w < 4; ++w) { wpre[w] = acc; acc += wsum[w]; }
        bsum[blockIdx.x] = acc;
    }
    __syncthreads();
    if (i < NN) offs[i] = v - val + wpre[wid];   // exclusive within block
}

// stage 2: scan the block sums (SCAN_B=196 fits one block)
__global__ __launch_bounds__(256) void scan2_k(int* __restrict__ bsum,
                                               int* __restrict__ bpre) {
    const int t = threadIdx.x;
    const int lane = t & 63, wid = t >> 6;
    int val = (t < SCAN_B) ? bsum[t] : 0;
    int v = val;
    #pragma unroll
    for (int off = 1; off < 64; off <<= 1) {
        int o = __shfl_up(v, off);
        if (lane >= off) v += o;
    }
    __shared__ int wsum[4], wpre[4];
    if (lane == 63) wsum[wid] = v;
    __syncthreads();
    if (t == 0) {
        int acc = 0;
        #pragma unroll
        for (int w = 0; w < 4; ++w) { wpre[w] = acc; acc += wsum[w]; }
    }
    __syncthreads();
    if (t < SCAN_B) bpre[t] = v - val + wpre[wid];
}

// stage 3: add block prefix, emit final offs + cursor
__global__ __launch_bounds__(256) void scan3_k(const int* __restrict__ bpre,
                                               int* __restrict__ offs,
                                               int* __restrict__ cursor) {
    const int i = blockIdx.x * 256 + threadIdx.x;
    if (i < NN) {
        int o = offs[i] + bpre[blockIdx.x];
        offs[i] = o;
        cursor[i] = o;
    }
    if (i == 0) offs[NN] = ET;   // total is a compile-time constant
}

// ---------------- CSR scatter (edges + self loops), also emits col ----------------
__global__ __launch_bounds__(256) void scatter_k(const int* __restrict__ ei,
                                                 int* __restrict__ cursor,
                                                 int* __restrict__ csr,
                                                 int* __restrict__ ccol) {
    int e = blockIdx.x * 256 + threadIdx.x;
    if (e >= ET) return;
    int r, c;
    if (e < NE) { r = ei[e]; c = ei[NE + e]; } else { r = e - NE; c = r; }
    int pos = atomicAdd(cursor + r, 1);
    csr[pos] = e;
    ccol[pos] = c;
}

// ---------------- fused: per-lane top-k+softmax, per-wave aggregate ----------------
// phase 1: thread t handles (row = rbase + t/4, head = t&3) serially:
//   insertion top-8 by u64 key (sortable-float(s_j) << 32 | ~eid) — exact
//   lexsort order (larger e wins, ties -> smaller eid; leaky_relu(s_i+s_j)
//   strictly monotone in s_j, s_i row-constant => select by s_j).
//   Order-independent -> CSR ordering/stability irrelevant.
// phase 2: wave w aggregates rows rbase + w*16 .. +15 with coalesced 128 B
//   gathers of h[col], ELU, store.
__global__ __launch_bounds__(256) void rowsel_k(const int* __restrict__ offs,
                                                const int* __restrict__ csr,
                                                const int* __restrict__ ccol,
                                                const float* __restrict__ s_i,
                                                const float* __restrict__ s_j,
                                                const float* __restrict__ hbuf,
                                                float* __restrict__ out) {
    __shared__ float lal[256 * 8];   // alpha (already /denom)
    __shared__ int   lcl[256 * 8];   // col
    const int t = threadIdx.x;
    const int rbase = blockIdx.x * 64;
    const int row = rbase + (t >> 2);
    const int head = t & 3;

    if (row < NN) {
        int o0 = offs[row];
        int dg = offs[row + 1] - o0;
        u64 kl[TOPK]; int cl[TOPK];
        #pragma unroll
        for (int i = 0; i < TOPK; ++i) { kl[i] = 0ull; cl[i] = 0; }
        for (int j = 0; j < dg; ++j) {
            int eid = csr[o0 + j];
            int col = ccol[o0 + j];
            float v = s_j[(size_t)col * 4 + head];
            u32 b = __float_as_uint(v);
            u32 fk = (b & 0x80000000u) ? ~b : (b | 0x80000000u);
            u64 key = ((u64)fk << 32) | (u32)(~(u32)eid);
            #pragma unroll
            for (int i = 0; i < TOPK; ++i) {
                bool gt = key > kl[i];
                u64 tk = gt ? kl[i] : key;  kl[i] = gt ? key : kl[i];  key = tk;
                int tc = gt ? cl[i] : col;  cl[i] = gt ? col : cl[i];  col = tc;
            }
        }
        int nk = (dg < TOPK) ? dg : TOPK;
        float si = s_i[(size_t)row * 4 + head];
        float al[TOPK];
        float m = 0.f;
        #pragma unroll
        for (int i = 0; i < TOPK; ++i) {
            u32 fk = (u32)(kl[i] >> 32);
            u32 b = (fk & 0x80000000u) ? (fk ^ 0x80000000u) : ~fk;
            float v = __uint_as_float(b);
            float e = si + v;
            e = (e >= 0.f) ? e : 0.2f * e;
            al[i] = e;
            if (i == 0) m = e;      // kl[0] is the max key -> max e
        }
        float denom = 0.f;
        #pragma unroll
        for (int i = 0; i < TOPK; ++i) {
            float z = (i < nk) ? __expf(al[i] - m) : 0.f;
            al[i] = z; denom += z;
        }
        float inv = 1.f / denom;
        #pragma unroll
        for (int i = 0; i < TOPK; ++i) {
            lal[t * 8 + i] = al[i] * inv;
            lcl[t * 8 + i] = cl[i];
        }
    }
    __syncthreads();

    const int lane = t & 63;
    const int wid = t >> 6;
    const int c = lane & 31, half = lane >> 5;
    for (int i = 0; i < 16; ++i) {
        int lr = wid * 16 + i;
        int r = rbase + lr;
        if (r >= NN) break;          // r uniform per wave
        #pragma unroll
        for (int hh = 0; hh < 4; ++hh) {
            int lrh = (lr * 4 + hh) * 8;
            float acc = 0.f;
            #pragma unroll
            for (int k2 = half; k2 < TOPK; k2 += 2) {
                float a = lal[lrh + k2];
                int col = lcl[lrh + k2];
                acc += a * hbuf[(size_t)col * 128 + hh * 32 + c];
            }
            acc += __shfl_xor(acc, 32);
            if (half == 0) {
                float o = acc;
                o = (o > 0.f) ? o : expm1f(o);   // ELU
                out[(size_t)r * 128 + hh * 32 + c] = o;
            }
        }
    }
}

extern "C" void kernel_launch(void* const* d_in, const int* in_sizes, int n_in,
                              void* d_out, int out_size, void* d_ws, size_t ws_size,
                              hipStream_t stream) {
    const float* x   = (const float*)d_in[0];   // 50000x128 f32
    const float* W   = (const float*)d_in[1];   // 128x128  f32
    const float* att = (const float*)d_in[2];   // 4x64     f32
    const int*   ei  = (const int*)d_in[3];     // 2x800000 int32
    float* out = (float*)d_out;                 // 50000x128 f32

    float* hbuf  = (float*)d_ws;                // 6.4M f32  (25.6 MB)
    float* s_i   = hbuf + 6400000;              // 200k f32
    float* s_j   = s_i + 200000;                // 200k f32
    int* deg     = (int*)(s_j + 200000);        // 50k
    int* offs    = deg + NN;                    // 50001
    int* cursor  = offs + NN + 1;               // 50k
    int* csr     = cursor + NN;                 // 850k
    int* ccol    = csr + ET;                    // 850k
    int* bsum    = ccol + ET;                   // 196
    int* bpre    = bsum + SCAN_B;               // 196
    // total ws: ~34.8 MB

    hipMemsetAsync(deg, 0, NN * sizeof(int), stream);
    gemm_k<<<(NN + 63) / 64, 256, 0, stream>>>(x, W, hbuf);
    s_k<<<(NN * 4 + 255) / 256, 256, 0, stream>>>(hbuf, att, s_i, s_j);
    deg_k<<<(NE + 255) / 256, 256, 0, stream>>>(ei, deg);
    scan1_k<<<SCAN_B, 256, 0, stream>>>(deg, offs, bsum);
    scan2_k<<<1, 256, 0, stream>>>(bsum, bpre);
    scan3_k<<<SCAN_B, 256, 0, stream>>>(bpre, offs, cursor);
    scatter_k<<<(ET + 255) / 256, 256, 0, stream>>>(ei, cursor, csr, ccol);
    rowsel_k<<<(NN + 63) / 64, 256, 0, stream>>>(offs, csr, ccol, s_i, s_j, hbuf, out);
}

// Round 5
// 257.291 us; speedup vs baseline: 2.7637x; 1.1362x over previous
//
#include <hip/hip_runtime.h>
#include <math.h>

typedef unsigned int u32;
typedef unsigned long long u64;

#define NN 50000
#define NE 800000
#define ET (NE + NN)          // edges + self loops
#define TOPK 8
#define SCAN_B 196            // ceil(50000/256)

__device__ __forceinline__ u64 shflxor64(u64 v, int m) {
    int lo = __shfl_xor((int)(u32)v, m);
    int hi = __shfl_xor((int)(u32)(v >> 32), m);
    return ((u64)(u32)hi << 32) | (u32)lo;
}

// ---------------- h = x @ W + fused s_i/s_j ----------------
// BM=128 rows/block, BK=64 two chunks. x staged k-major (xst[k][r], pad 132)
// so compute reads are b128 over rows, conflict-free. 8x8 register tile.
// LDS 65 KB -> 2 blocks/CU. Epilogue computes s_i/s_j (dot with att) via
// 4-lane shuffle reduction, eliminating the separate s_k pass over h.
__global__ __launch_bounds__(256) void gemm_k(const float* __restrict__ x,
                                              const float* __restrict__ W,
                                              const float* __restrict__ att,
                                              float* __restrict__ hbuf,
                                              float* __restrict__ s_i,
                                              float* __restrict__ s_j) {
    __shared__ float xst[64][132];    // [k][r] transposed, 33.8 KB
    __shared__ float ws[64][128];     // [k][c], 32 KB
    const int t = threadIdx.x;
    const int cx = t & 15;            // col group: cols cx*8..+7
    const int ry = t >> 4;            // row group: rows ry*8..+7
    const int rbase = blockIdx.x * 128;

    float acc[8][8];
    #pragma unroll
    for (int i = 0; i < 8; ++i)
        #pragma unroll
        for (int j = 0; j < 8; ++j) acc[i][j] = 0.f;

    for (int kk = 0; kk < 128; kk += 64) {
        if (kk) __syncthreads();
        // stage x: thread reads x[rbase+rr][kk + cx*4 .. +3] (coalesced),
        // writes transposed scalar.
        #pragma unroll
        for (int rr = ry; rr < 128; rr += 16) {
            int gr = rbase + rr;
            float4 v = make_float4(0.f, 0.f, 0.f, 0.f);
            if (gr < NN)
                v = *reinterpret_cast<const float4*>(x + (size_t)gr * 128 + kk + cx * 4);
            xst[cx * 4 + 0][rr] = v.x;
            xst[cx * 4 + 1][rr] = v.y;
            xst[cx * 4 + 2][rr] = v.z;
            xst[cx * 4 + 3][rr] = v.w;
        }
        // stage W: thread reads W[kk+wk][(t&31)*4 ..] (coalesced full rows)
        #pragma unroll
        for (int wk = t >> 5; wk < 64; wk += 8) {
            float4 v = *reinterpret_cast<const float4*>(W + (size_t)(kk + wk) * 128 + (t & 31) * 4);
            *reinterpret_cast<float4*>(&ws[wk][(t & 31) * 4]) = v;
        }
        __syncthreads();

        for (int k = 0; k < 64; ++k) {
            float4 xa = *reinterpret_cast<const float4*>(&xst[k][ry * 8]);
            float4 xb = *reinterpret_cast<const float4*>(&xst[k][ry * 8 + 4]);
            float4 wa = *reinterpret_cast<const float4*>(&ws[k][cx * 8]);
            float4 wb = *reinterpret_cast<const float4*>(&ws[k][cx * 8 + 4]);
            float xv[8] = {xa.x, xa.y, xa.z, xa.w, xb.x, xb.y, xb.z, xb.w};
            float wv[8] = {wa.x, wa.y, wa.z, wa.w, wb.x, wb.y, wb.z, wb.w};
            #pragma unroll
            for (int i = 0; i < 8; ++i)
                #pragma unroll
                for (int j = 0; j < 8; ++j) acc[i][j] += xv[i] * wv[j];
        }
    }

    // epilogue: store h + fused s_i/s_j
    const int head = cx >> 2;                   // cols cx*8 within head
    float aiv[8], ajv[8];
    #pragma unroll
    for (int j = 0; j < 8; ++j) {
        aiv[j] = att[head * 64 + (cx & 3) * 8 + j];
        ajv[j] = att[head * 64 + 32 + (cx & 3) * 8 + j];
    }
    #pragma unroll
    for (int i = 0; i < 8; ++i) {
        int gr = rbase + ry * 8 + i;
        float pi = 0.f, pj = 0.f;
        #pragma unroll
        for (int j = 0; j < 8; ++j) {
            pi += acc[i][j] * aiv[j];
            pj += acc[i][j] * ajv[j];
        }
        pi += __shfl_xor(pi, 1); pi += __shfl_xor(pi, 2);
        pj += __shfl_xor(pj, 1); pj += __shfl_xor(pj, 2);
        if (gr < NN) {
            float* dst = hbuf + (size_t)gr * 128 + cx * 8;
            *reinterpret_cast<float4*>(dst)     = make_float4(acc[i][0], acc[i][1], acc[i][2], acc[i][3]);
            *reinterpret_cast<float4*>(dst + 4) = make_float4(acc[i][4], acc[i][5], acc[i][6], acc[i][7]);
            if ((cx & 3) == 0) {
                s_i[(size_t)gr * 4 + head] = pi;
                s_j[(size_t)gr * 4 + head] = pj;
            }
        }
    }
}

// ---------------- degree count (real edges only), x4 vectorized ----------------
__global__ __launch_bounds__(256) void deg_k(const int* __restrict__ ei,
                                             int* __restrict__ deg) {
    int e4 = (blockIdx.x * 256 + threadIdx.x) * 4;
    if (e4 >= NE) return;
    int4 v = *reinterpret_cast<const int4*>(ei + e4);
    atomicAdd(deg + v.x, 1);
    atomicAdd(deg + v.y, 1);
    atomicAdd(deg + v.z, 1);
    atomicAdd(deg + v.w, 1);
}

// ---------------- scan stage 1: per-block scan of deg[i]+1 ----------------
__global__ __launch_bounds__(256) void scan1_k(const int* __restrict__ deg,
                                               int* __restrict__ offs,
                                               int* __restrict__ bsum) {
    const int t = threadIdx.x;
    const int lane = t & 63, wid = t >> 6;
    const int i = blockIdx.x * 256 + t;
    int val = (i < NN) ? (deg[i] + 1) : 0;
    int v = val;
    #pragma unroll
    for (int off = 1; off < 64; off <<= 1) {
        int o = __shfl_up(v, off);
        if (lane >= off) v += o;
    }
    __shared__ int wsum[4], wpre[4];
    if (lane == 63) wsum[wid] = v;
    __syncthreads();
    if (t == 0) {
        int acc = 0;
        #pragma unroll
        for (int w = 0; w < 4; ++w) { wpre[w] = acc; acc += wsum[w]; }
        bsum[blockIdx.x] = acc;
    }
    __syncthreads();
    if (i < NN) offs[i] = v - val + wpre[wid];   // exclusive within block
}

// ---------------- scan stage 2+3 fused: block prefix + final offs/cursor ----------------
__global__ __launch_bounds__(256) void scan3_k(const int* __restrict__ bsum,
                                               int* __restrict__ offs,
                                               int* __restrict__ cursor) {
    const int t = threadIdx.x;
    const int b = blockIdx.x;
    const int lane = t & 63, wid = t >> 6;
    // prefix = sum of bsum[0..b)  (b < 256, one element per thread)
    int v = (t < b) ? bsum[t] : 0;
    #pragma unroll
    for (int off = 1; off < 64; off <<= 1) v += __shfl_xor(v, off);
    __shared__ int wsum[4];
    __shared__ int pre;
    if (lane == 0) wsum[wid] = v;
    __syncthreads();
    if (t == 0) pre = wsum[0] + wsum[1] + wsum[2] + wsum[3];
    __syncthreads();
    const int i = b * 256 + t;
    if (i < NN) {
        int o = offs[i] + pre;
        offs[i] = o;
        cursor[i] = o;
    }
    if (b == 0 && t == 0) offs[NN] = ET;
}

// ---------------- CSR scatter, x2, packed (col<<32 | eid) ----------------
__global__ __launch_bounds__(256) void scatter_k(const int* __restrict__ ei,
                                                 int* __restrict__ cursor,
                                                 u64* __restrict__ ccsr) {
    int e = (blockIdx.x * 256 + threadIdx.x) * 2;
    if (e >= ET) return;
    #pragma unroll
    for (int q = 0; q < 2; ++q) {
        int ee = e + q;
        int r, c;
        if (ee < NE) { r = ei[ee]; c = ei[NE + ee]; } else { r = ee - NE; c = r; }
        int pos = atomicAdd(cursor + r, 1);
        ccsr[pos] = ((u64)(u32)c << 32) | (u32)ee;
    }
}

// ---------------- fused: split-half top-k + bitonic merge + softmax + aggregate ----------------
// 32 rows/block. Phase 1: 8 threads per row = 4 heads x 2 halves; each half
// insertion-sorts top-8 of its interleaved half of the edges, then the pair
// merges via max(A[i], B[7-i]) (top-8 of union of two sorted-desc lists).
// Keys (sortable-float(s_j)<<32 | ~eid) are unique -> exact lexsort order.
// Phase 2: wave w aggregates rows w*8..+7 with coalesced 128 B gathers.
__global__ __launch_bounds__(256) void rowsel_k(const int* __restrict__ offs,
                                                const u64* __restrict__ ccsr,
                                                const float* __restrict__ s_i,
                                                const float* __restrict__ s_j,
                                                const float* __restrict__ hbuf,
                                                float* __restrict__ out) {
    __shared__ float lal[32 * 4 * 8];   // normalized alpha
    __shared__ int   lcl[32 * 4 * 8];   // col
    const int t = threadIdx.x;
    const int rbase = blockIdx.x * 32;
    const int lr = t >> 3;
    const int head = (t >> 1) & 3;
    const int half = t & 1;
    const int row = rbase + lr;

    u64 kl[TOPK];
    int cl[TOPK];
    #pragma unroll
    for (int i = 0; i < TOPK; ++i) { kl[i] = 0ull; cl[i] = 0; }

    int o0 = 0, dg = 0;
    if (row < NN) { o0 = offs[row]; dg = offs[row + 1] - o0; }
    for (int j = half; j < dg; j += 2) {
        u64 pk = ccsr[o0 + j];
        int col = (int)(pk >> 32);
        u32 eid = (u32)pk;
        float v = s_j[(size_t)col * 4 + head];
        u32 b = __float_as_uint(v);
        u32 fk = (b & 0x80000000u) ? ~b : (b | 0x80000000u);
        u64 key = ((u64)fk << 32) | (u32)(~eid);
        int cc = col;
        #pragma unroll
        for (int i = 0; i < TOPK; ++i) {
            bool gt = key > kl[i];
            u64 tk = gt ? kl[i] : key;  kl[i] = gt ? key : kl[i];  key = tk;
            int tc = gt ? cl[i] : cc;   cl[i] = gt ? cc : cl[i];   cc = tc;
        }
    }

    // merge with partner (t^1): top-8 of union = max(A[i], B[7-i])
    u64 mk[TOPK]; int mc[TOPK];
    #pragma unroll
    for (int i = 0; i < TOPK; ++i) {
        u64 pk = shflxor64(kl[TOPK - 1 - i], 1);
        int pc = __shfl_xor(cl[TOPK - 1 - i], 1);
        bool mine = kl[i] >= pk;
        mk[i] = mine ? kl[i] : pk;
        mc[i] = mine ? cl[i] : pc;
    }
    u64 pk0 = shflxor64(kl[0], 1);
    u64 mxk = (kl[0] >= pk0) ? kl[0] : pk0;

    float si = (row < NN) ? s_i[(size_t)row * 4 + head] : 0.f;
    {
        u32 fk = (u32)(mxk >> 32);
        u32 b = (fk & 0x80000000u) ? (fk ^ 0x80000000u) : ~fk;
        float vmax = __uint_as_float(b);
        float em = si + vmax;
        float m = (em >= 0.f) ? em : 0.2f * em;
        float al[TOPK];
        float denom = 0.f;
        #pragma unroll
        for (int i = 0; i < TOPK; ++i) {
            u32 fki = (u32)(mk[i] >> 32);
            u32 bi = (fki & 0x80000000u) ? (fki ^ 0x80000000u) : ~fki;
            float v = __uint_as_float(bi);
            float e = si + v;
            e = (e >= 0.f) ? e : 0.2f * e;
            float z = (mk[i] != 0ull) ? __expf(e - m) : 0.f;
            al[i] = z;
            denom += z;
        }
        float inv = 1.f / denom;
        if (row < NN && half == 0) {
            const int base = (lr * 4 + head) * 8;
            #pragma unroll
            for (int i = 0; i < TOPK; ++i) {
                lal[base + i] = al[i] * inv;
                lcl[base + i] = mc[i];
            }
        }
    }
    __syncthreads();

    // phase 2: wave wid handles rows wid*8..+7
    const int lane = t & 63;
    const int wid = t >> 6;
    const int c = lane & 31, hw = lane >> 5;
    for (int i = 0; i < 8; ++i) {
        int lr2 = wid * 8 + i;
        int r = rbase + lr2;
        if (r >= NN) break;           // wave-uniform
        #pragma unroll
        for (int hh = 0; hh < 4; ++hh) {
            const int base = (lr2 * 4 + hh) * 8;
            float acc = 0.f;
            #pragma unroll
            for (int k2 = hw; k2 < TOPK; k2 += 2) {
                float a = lal[base + k2];
                int col = lcl[base + k2];
                acc += a * hbuf[(size_t)col * 128 + hh * 32 + c];
            }
            acc += __shfl_xor(acc, 32);
            if (hw == 0) {
                float o = acc;
                o = (o > 0.f) ? o : expm1f(o);   // ELU
                out[(size_t)r * 128 + hh * 32 + c] = o;
            }
        }
    }
}

extern "C" void kernel_launch(void* const* d_in, const int* in_sizes, int n_in,
                              void* d_out, int out_size, void* d_ws, size_t ws_size,
                              hipStream_t stream) {
    const float* x   = (const float*)d_in[0];   // 50000x128 f32
    const float* W   = (const float*)d_in[1];   // 128x128  f32
    const float* att = (const float*)d_in[2];   // 4x64     f32
    const int*   ei  = (const int*)d_in[3];     // 2x800000 int32
    float* out = (float*)d_out;                 // 50000x128 f32

    u64* ccsr    = (u64*)d_ws;                  // 850k u64 (8-aligned at base)
    float* hbuf  = (float*)(ccsr + ET);         // 6.4M f32
    float* s_i   = hbuf + 6400000;              // 200k f32
    float* s_j   = s_i + 200000;                // 200k f32
    int* deg     = (int*)(s_j + 200000);        // 50k
    int* offs    = deg + NN;                    // 50001
    int* cursor  = offs + NN + 1;               // 50k
    int* bsum    = cursor + NN;                 // 196
    // total ws: ~34.7 MB

    hipMemsetAsync(deg, 0, NN * sizeof(int), stream);
    gemm_k<<<(NN + 127) / 128, 256, 0, stream>>>(x, W, att, hbuf, s_i, s_j);
    deg_k<<<(NE / 4 + 255) / 256, 256, 0, stream>>>(ei, deg);
    scan1_k<<<SCAN_B, 256, 0, stream>>>(deg, offs, bsum);
    scan3_k<<<SCAN_B, 256, 0, stream>>>(bsum, offs, cursor);
    scatter_k<<<(ET / 2 + 255) / 256, 256, 0, stream>>>(ei, cursor, ccsr);
    rowsel_k<<<(NN + 31) / 32, 256, 0, stream>>>(offs, ccsr, s_i, s_j, hbuf, out);
}

// Round 6
// 207.120 us; speedup vs baseline: 3.4331x; 1.2422x over previous
//
#include <hip/hip_runtime.h>
#include <math.h>

typedef unsigned int u32;
typedef unsigned long long u64;

#define NN 50000
#define NE 800000
#define TOPK 8
#define SCAN_B 196            // ceil(50000/256)

__device__ __forceinline__ u64 shflxor64(u64 v, int m) {
    int lo = __shfl_xor((int)(u32)v, m);
    int hi = __shfl_xor((int)(u32)(v >> 32), m);
    return ((u64)(u32)hi << 32) | (u32)lo;
}

// ---------------- h = x @ W + fused s_i/s_j ----------------
// BM=128 rows/block, BK=64 two chunks. x staged k-major (xst[k][r], pad 132)
// so compute reads are b128 over rows, conflict-free. 8x8 register tile.
// LDS 65 KB -> 2 blocks/CU. Epilogue computes s_i/s_j (dot with att) via
// 4-lane shuffle reduction, eliminating a separate pass over h.
__global__ __launch_bounds__(256) void gemm_k(const float* __restrict__ x,
                                              const float* __restrict__ W,
                                              const float* __restrict__ att,
                                              float* __restrict__ hbuf,
                                              float* __restrict__ s_i,
                                              float* __restrict__ s_j) {
    __shared__ float xst[64][132];    // [k][r] transposed, 33.8 KB
    __shared__ float ws[64][128];     // [k][c], 32 KB
    const int t = threadIdx.x;
    const int cx = t & 15;            // col group: cols cx*8..+7
    const int ry = t >> 4;            // row group: rows ry*8..+7
    const int rbase = blockIdx.x * 128;

    float acc[8][8];
    #pragma unroll
    for (int i = 0; i < 8; ++i)
        #pragma unroll
        for (int j = 0; j < 8; ++j) acc[i][j] = 0.f;

    for (int kk = 0; kk < 128; kk += 64) {
        if (kk) __syncthreads();
        #pragma unroll
        for (int rr = ry; rr < 128; rr += 16) {
            int gr = rbase + rr;
            float4 v = make_float4(0.f, 0.f, 0.f, 0.f);
            if (gr < NN)
                v = *reinterpret_cast<const float4*>(x + (size_t)gr * 128 + kk + cx * 4);
            xst[cx * 4 + 0][rr] = v.x;
            xst[cx * 4 + 1][rr] = v.y;
            xst[cx * 4 + 2][rr] = v.z;
            xst[cx * 4 + 3][rr] = v.w;
        }
        #pragma unroll
        for (int wk = t >> 5; wk < 64; wk += 8) {
            float4 v = *reinterpret_cast<const float4*>(W + (size_t)(kk + wk) * 128 + (t & 31) * 4);
            *reinterpret_cast<float4*>(&ws[wk][(t & 31) * 4]) = v;
        }
        __syncthreads();

        for (int k = 0; k < 64; ++k) {
            float4 xa = *reinterpret_cast<const float4*>(&xst[k][ry * 8]);
            float4 xb = *reinterpret_cast<const float4*>(&xst[k][ry * 8 + 4]);
            float4 wa = *reinterpret_cast<const float4*>(&ws[k][cx * 8]);
            float4 wb = *reinterpret_cast<const float4*>(&ws[k][cx * 8 + 4]);
            float xv[8] = {xa.x, xa.y, xa.z, xa.w, xb.x, xb.y, xb.z, xb.w};
            float wv[8] = {wa.x, wa.y, wa.z, wa.w, wb.x, wb.y, wb.z, wb.w};
            #pragma unroll
            for (int i = 0; i < 8; ++i)
                #pragma unroll
                for (int j = 0; j < 8; ++j) acc[i][j] += xv[i] * wv[j];
        }
    }

    // epilogue: store h + fused s_i/s_j
    const int head = cx >> 2;
    float aiv[8], ajv[8];
    #pragma unroll
    for (int j = 0; j < 8; ++j) {
        aiv[j] = att[head * 64 + (cx & 3) * 8 + j];
        ajv[j] = att[head * 64 + 32 + (cx & 3) * 8 + j];
    }
    #pragma unroll
    for (int i = 0; i < 8; ++i) {
        int gr = rbase + ry * 8 + i;
        float pi = 0.f, pj = 0.f;
        #pragma unroll
        for (int j = 0; j < 8; ++j) {
            pi += acc[i][j] * aiv[j];
            pj += acc[i][j] * ajv[j];
        }
        pi += __shfl_xor(pi, 1); pi += __shfl_xor(pi, 2);
        pj += __shfl_xor(pj, 1); pj += __shfl_xor(pj, 2);
        if (gr < NN) {
            float* dst = hbuf + (size_t)gr * 128 + cx * 8;
            *reinterpret_cast<float4*>(dst)     = make_float4(acc[i][0], acc[i][1], acc[i][2], acc[i][3]);
            *reinterpret_cast<float4*>(dst + 4) = make_float4(acc[i][4], acc[i][5], acc[i][6], acc[i][7]);
            if ((cx & 3) == 0) {
                s_i[(size_t)gr * 4 + head] = pi;
                s_j[(size_t)gr * 4 + head] = pj;
            }
        }
    }
}

// ---------------- degree + per-edge rank (atomic return), x4 ----------------
__global__ __launch_bounds__(256) void deg_k(const int* __restrict__ ei,
                                             int* __restrict__ deg,
                                             int* __restrict__ rank) {
    int e4 = (blockIdx.x * 256 + threadIdx.x) * 4;
    if (e4 >= NE) return;
    int4 v = *reinterpret_cast<const int4*>(ei + e4);
    int4 r;
    r.x = atomicAdd(deg + v.x, 1);
    r.y = atomicAdd(deg + v.y, 1);
    r.z = atomicAdd(deg + v.z, 1);
    r.w = atomicAdd(deg + v.w, 1);
    *reinterpret_cast<int4*>(rank + e4) = r;
}

// ---------------- scan stage 1: per-block scan of deg[i] ----------------
__global__ __launch_bounds__(256) void scan1_k(const int* __restrict__ deg,
                                               int* __restrict__ offs,
                                               int* __restrict__ bsum) {
    const int t = threadIdx.x;
    const int lane = t & 63, wid = t >> 6;
    const int i = blockIdx.x * 256 + t;
    int val = (i < NN) ? deg[i] : 0;
    int v = val;
    #pragma unroll
    for (int off = 1; off < 64; off <<= 1) {
        int o = __shfl_up(v, off);
        if (lane >= off) v += o;
    }
    __shared__ int wsum[4], wpre[4];
    if (lane == 63) wsum[wid] = v;
    __syncthreads();
    if (t == 0) {
        int acc = 0;
        #pragma unroll
        for (int w = 0; w < 4; ++w) { wpre[w] = acc; acc += wsum[w]; }
        bsum[blockIdx.x] = acc;
    }
    __syncthreads();
    if (i < NN) offs[i] = v - val + wpre[wid];   // exclusive within block
}

// ---------------- scan stage 2+3 fused: block prefix + final offs ----------------
__global__ __launch_bounds__(256) void scan3_k(const int* __restrict__ bsum,
                                               int* __restrict__ offs) {
    const int t = threadIdx.x;
    const int b = blockIdx.x;
    const int lane = t & 63, wid = t >> 6;
    int v = (t < b) ? bsum[t] : 0;
    #pragma unroll
    for (int off = 1; off < 64; off <<= 1) v += __shfl_xor(v, off);
    __shared__ int wsum[4];
    __shared__ int pre;
    if (lane == 0) wsum[wid] = v;
    __syncthreads();
    if (t == 0) pre = wsum[0] + wsum[1] + wsum[2] + wsum[3];
    __syncthreads();
    const int i = b * 256 + t;
    if (i < NN) offs[i] += pre;
    if (b == 0 && t == 0) offs[NN] = NE;
}

// ---------------- CSR scatter: NO atomic (pos = offs[r] + rank[e]), x2 ----------------
__global__ __launch_bounds__(256) void scatter_k(const int* __restrict__ ei,
                                                 const int* __restrict__ rank,
                                                 const int* __restrict__ offs,
                                                 u64* __restrict__ ccsr) {
    int e = (blockIdx.x * 256 + threadIdx.x) * 2;
    if (e >= NE) return;
    int2 rr = *reinterpret_cast<const int2*>(ei + e);
    int2 cc = *reinterpret_cast<const int2*>(ei + NE + e);
    int2 rk = *reinterpret_cast<const int2*>(rank + e);
    int p0 = offs[rr.x] + rk.x;
    int p1 = offs[rr.y] + rk.y;
    ccsr[p0] = ((u64)(u32)cc.x << 32) | (u32)e;
    ccsr[p1] = ((u64)(u32)cc.y << 32) | (u32)(e + 1);
}

// ---------------- fused: split-half top-k + merge + softmax + aggregate ----------------
// 32 rows/block; 8 threads/row = 4 heads x 2 halves. Self-loop candidate
// (col=row, eid=NE+row) synthesized in half 0 — never materialized in CSR.
// Keys (sortable-float(s_j)<<32 | ~eid) unique -> exact lexsort order.
__global__ __launch_bounds__(256) void rowsel_k(const int* __restrict__ offs,
                                                const u64* __restrict__ ccsr,
                                                const float* __restrict__ s_i,
                                                const float* __restrict__ s_j,
                                                const float* __restrict__ hbuf,
                                                float* __restrict__ out) {
    __shared__ float lal[32 * 4 * 8];   // normalized alpha
    __shared__ int   lcl[32 * 4 * 8];   // col
    const int t = threadIdx.x;
    const int rbase = blockIdx.x * 32;
    const int lr = t >> 3;
    const int head = (t >> 1) & 3;
    const int half = t & 1;
    const int row = rbase + lr;

    u64 kl[TOPK];
    int cl[TOPK];
    #pragma unroll
    for (int i = 0; i < TOPK; ++i) { kl[i] = 0ull; cl[i] = 0; }

    int o0 = 0, dg = 0;
    if (row < NN) { o0 = offs[row]; dg = offs[row + 1] - o0; }

    if (half == 0 && row < NN) {
        // synthetic self-loop candidate
        float v = s_j[(size_t)row * 4 + head];
        u32 b = __float_as_uint(v);
        u32 fk = (b & 0x80000000u) ? ~b : (b | 0x80000000u);
        u64 key = ((u64)fk << 32) | (u32)(~(u32)(NE + row));
        kl[0] = key; cl[0] = row;
    }

    for (int j = half; j < dg; j += 2) {
        u64 pk = ccsr[o0 + j];
        int col = (int)(pk >> 32);
        u32 eid = (u32)pk;
        float v = s_j[(size_t)col * 4 + head];
        u32 b = __float_as_uint(v);
        u32 fk = (b & 0x80000000u) ? ~b : (b | 0x80000000u);
        u64 key = ((u64)fk << 32) | (u32)(~eid);
        int cc = col;
        #pragma unroll
        for (int i = 0; i < TOPK; ++i) {
            bool gt = key > kl[i];
            u64 tk = gt ? kl[i] : key;  kl[i] = gt ? key : kl[i];  key = tk;
            int tc = gt ? cl[i] : cc;   cl[i] = gt ? cc : cl[i];   cc = tc;
        }
    }

    // merge with partner (t^1): top-8 of union = max(A[i], B[7-i])
    u64 mk[TOPK]; int mc[TOPK];
    #pragma unroll
    for (int i = 0; i < TOPK; ++i) {
        u64 pk = shflxor64(kl[TOPK - 1 - i], 1);
        int pc = __shfl_xor(cl[TOPK - 1 - i], 1);
        bool mine = kl[i] >= pk;
        mk[i] = mine ? kl[i] : pk;
        mc[i] = mine ? cl[i] : pc;
    }
    u64 pk0 = shflxor64(kl[0], 1);
    u64 mxk = (kl[0] >= pk0) ? kl[0] : pk0;

    float si = (row < NN) ? s_i[(size_t)row * 4 + head] : 0.f;
    {
        u32 fk = (u32)(mxk >> 32);
        u32 b = (fk & 0x80000000u) ? (fk ^ 0x80000000u) : ~fk;
        float vmax = __uint_as_float(b);
        float em = si + vmax;
        float m = (em >= 0.f) ? em : 0.2f * em;
        float al[TOPK];
        float denom = 0.f;
        #pragma unroll
        for (int i = 0; i < TOPK; ++i) {
            u32 fki = (u32)(mk[i] >> 32);
            u32 bi = (fki & 0x80000000u) ? (fki ^ 0x80000000u) : ~fki;
            float v = __uint_as_float(bi);
            float e = si + v;
            e = (e >= 0.f) ? e : 0.2f * e;
            float z = (mk[i] != 0ull) ? __expf(e - m) : 0.f;
            al[i] = z;
            denom += z;
        }
        float inv = 1.f / denom;
        if (row < NN && half == 0) {
            const int base = (lr * 4 + head) * 8;
            #pragma unroll
            for (int i = 0; i < TOPK; ++i) {
                lal[base + i] = al[i] * inv;
                lcl[base + i] = mc[i];
            }
        }
    }
    __syncthreads();

    // phase 2: wave wid aggregates rows wid*8..+7, coalesced 128 B gathers
    const int lane = t & 63;
    const int wid = t >> 6;
    const int c = lane & 31, hw = lane >> 5;
    for (int i = 0; i < 8; ++i) {
        int lr2 = wid * 8 + i;
        int r = rbase + lr2;
        if (r >= NN) break;           // wave-uniform
        #pragma unroll
        for (int hh = 0; hh < 4; ++hh) {
            const int base = (lr2 * 4 + hh) * 8;
            float acc = 0.f;
            #pragma unroll
            for (int k2 = hw; k2 < TOPK; k2 += 2) {
                float a = lal[base + k2];
                int col = lcl[base + k2];
                acc += a * hbuf[(size_t)col * 128 + hh * 32 + c];
            }
            acc += __shfl_xor(acc, 32);
            if (hw == 0) {
                float o = acc;
                o = (o > 0.f) ? o : expm1f(o);   // ELU
                out[(size_t)r * 128 + hh * 32 + c] = o;
            }
        }
    }
}

extern "C" void kernel_launch(void* const* d_in, const int* in_sizes, int n_in,
                              void* d_out, int out_size, void* d_ws, size_t ws_size,
                              hipStream_t stream) {
    const float* x   = (const float*)d_in[0];   // 50000x128 f32
    const float* W   = (const float*)d_in[1];   // 128x128  f32
    const float* att = (const float*)d_in[2];   // 4x64     f32
    const int*   ei  = (const int*)d_in[3];     // 2x800000 int32
    float* out = (float*)d_out;                 // 50000x128 f32

    u64* ccsr    = (u64*)d_ws;                  // 800k u64 (8-aligned at base)
    float* hbuf  = (float*)(ccsr + NE);         // 6.4M f32
    float* s_i   = hbuf + 6400000;              // 200k f32
    float* s_j   = s_i + 200000;                // 200k f32
    int* deg     = (int*)(s_j + 200000);        // 50k
    int* offs    = deg + NN;                    // 50001
    int* rank    = offs + NN + 1;               // 800k
    int* bsum    = rank + NE;                   // 196
    // total ws: ~37 MB

    hipMemsetAsync(deg, 0, NN * sizeof(int), stream);
    gemm_k<<<(NN + 127) / 128, 256, 0, stream>>>(x, W, att, hbuf, s_i, s_j);
    deg_k<<<(NE / 4 + 255) / 256, 256, 0, stream>>>(ei, deg, rank);
    scan1_k<<<SCAN_B, 256, 0, stream>>>(deg, offs, bsum);
    scan3_k<<<SCAN_B, 256, 0, stream>>>(bsum, offs);
    scatter_k<<<(NE / 2 + 255) / 256, 256, 0, stream>>>(ei, rank, offs, ccsr);
    rowsel_k<<<(NN + 31) / 32, 256, 0, stream>>>(offs, ccsr, s_i, s_j, hbuf, out);
}